// Round 11
// baseline (1198.389 us; speedup 1.0000x reference)
//
#include <hip/hip_runtime.h>
#include <math.h>

#define BATCH     512
#define NBLK      256                    // 2 batch elements per block
#define T_PAST_   360
#define T_FUT_    1800
#define IN_SZ     3
#define H_SZ      64
#define FUT_SEQ   50
#define WSPF_     34
#define MAX_STEPS (FUT_SEQ * WSPF_)      // 1700
#define T_TOT     (T_PAST_ + MAX_STEPS)  // 2060
#define NTHREADS  256
#define PSTRIDE   66                     // wproj row stride (2-way banks = free)

typedef __fp16 h2 __attribute__((ext_vector_type(2)));

__device__ __forceinline__ h2  as_h2(int v) { return __builtin_bit_cast(h2, v); }
__device__ __forceinline__ int as_i(h2 v)   { return __builtin_bit_cast(int, v); }

__device__ __forceinline__ float rcp_(float x) { return __builtin_amdgcn_rcpf(x); }

__device__ __forceinline__ float tanh_(float x) {
    float a = fabsf(x);
    float e = __expf(-2.0f * a);         // in (0,1], no overflow
    float t = (1.0f - e) * rcp_(1.0f + e);
    return copysignf(t, x);
}

// packed-pair dot with f32 accumulate: D = a.x*b.x + a.y*b.y + c
__device__ __forceinline__ float dot2_(int a, int b, float c) {
#if __has_builtin(__builtin_amdgcn_fdot2)
    return __builtin_amdgcn_fdot2(as_h2(a), as_h2(b), c, false);
#else
    h2 av = as_h2(a), bv = as_h2(b);
    return fmaf((float)av.x, (float)bv.x, fmaf((float)av.y, (float)bv.y, c));
#endif
}

__device__ __forceinline__ int rl_(int v, int src) {
    return __builtin_amdgcn_readlane(v, src);
}

// neighbor (lane^1) value via DPP quad_perm [1,0,3,2] — pure VALU, no LDS
__device__ __forceinline__ float dpp_xor1_(float v) {
    return __builtin_bit_cast(float,
        __builtin_amdgcn_update_dpp(0, __builtin_bit_cast(int, v),
                                    0xB1, 0xF, 0xF, true));
}

// TWO batch elements per 256-thread block; thread = gate row for BOTH
// elements (W_hh is batch-invariant, so the 32 packed-fp16 weight VGPRs are
// shared — zero marginal cost). Element A's LDS latencies (gates read, h2
// broadcast read) hide under element B's independent VALU issue inside the
// SAME wave, instead of relying on the CU scheduler to dovetail two separate
// blocks (r9's residual ~750-cyc/step stall). One barrier per iteration now
// advances two element-steps.
__global__ __launch_bounds__(NTHREADS, 2)
void lstm_fused_kernel(const float* __restrict__ wave_input,   // [B, 360, 3]
                       const float* __restrict__ wave_future,  // [B, 1800, 3]
                       const float* __restrict__ W_ih,         // [256, 3]
                       const float* __restrict__ W_hh,         // [256, 64]
                       const float* __restrict__ b_ih,         // [256]
                       const float* __restrict__ b_hh,         // [256]
                       const float* __restrict__ W_proj,       // [64, 64]
                       const float* __restrict__ b_proj,       // [64]
                       float* __restrict__ out)                // [B, 50, 64]
{
    __shared__ __align__(16) float x_lds[2][T_TOT * IN_SZ];    // 49.4 KB
    __shared__ __align__(16) float wproj_lds[H_SZ * PSTRIDE];  // 16.9 KB
    __shared__ __align__(16) float gates_lds[2][2][NTHREADS];  // [elem][buf] 4 KB
    __shared__ __align__(16) int   h2_lds[2][4][2][H_SZ / 2];  // [elem][wv][buf] 2 KB

    const int b    = blockIdx.x;       // element A = b, element B = b + NBLK
    const int tid  = threadIdx.x;      // gate row 0..255
    const int wv   = tid >> 6;
    const int lane = tid & 63;         // hidden unit this thread updates

    // ---- stage both x sequences (coalesced, one-time) ----
    {
        const float* wiA = wave_input  + (size_t)b * (T_PAST_ * IN_SZ);
        const float* wiB = wave_input  + (size_t)(b + NBLK) * (T_PAST_ * IN_SZ);
        for (int i = tid; i < T_PAST_ * IN_SZ; i += NTHREADS) {
            x_lds[0][i] = wiA[i];
            x_lds[1][i] = wiB[i];
        }
        const float* wfA = wave_future + (size_t)b * (T_FUT_ * IN_SZ);
        const float* wfB = wave_future + (size_t)(b + NBLK) * (T_FUT_ * IN_SZ);
        for (int i = tid; i < MAX_STEPS * IN_SZ; i += NTHREADS) {
            x_lds[0][T_PAST_ * IN_SZ + i] = wfA[i];
            x_lds[1][T_PAST_ * IN_SZ + i] = wfB[i];
        }
    }
    for (int i = tid; i < H_SZ * H_SZ; i += NTHREADS) {
        int r = i >> 6, cc = i & 63;
        wproj_lds[r * PSTRIDE + cc] = W_proj[i];
    }
    if (lane < 32) {                   // zero h2 buffer 0 for step 0
        h2_lds[0][wv][0][lane] = 0;
        h2_lds[1][wv][0][lane] = 0;
    }

    // g-gate rows get the tanh(x)=2*sigmoid(2x)-1 scale folded into weights
    const bool  isg   = (tid >= 2 * H_SZ) && (tid < 3 * H_SZ);
    const float scale = isg ? 2.0f : 1.0f;
    const float aa    = isg ? 2.0f : 1.0f;
    const float bb    = isg ? -1.0f : 0.0f;

    // ---- W_hh row `tid` as 32 packed fp16 pairs (32 VGPRs, pinned) ----
    int w2[32];
    {
        const float* rowp = W_hh + (size_t)tid * H_SZ;
        #pragma unroll
        for (int j = 0; j < 32; ++j)
            w2[j] = as_i(__builtin_amdgcn_cvt_pkrtz(rowp[2*j]   * scale,
                                                    rowp[2*j+1] * scale));
    }
    #pragma unroll
    for (int k = 0; k < 32; k += 8)
        asm volatile("" : "+v"(w2[k+0]), "+v"(w2[k+1]), "+v"(w2[k+2]), "+v"(w2[k+3]),
                          "+v"(w2[k+4]), "+v"(w2[k+5]), "+v"(w2[k+6]), "+v"(w2[k+7]));

    const float wih0 = W_ih[tid * 3 + 0] * scale;
    const float wih1 = W_ih[tid * 3 + 1] * scale;
    const float wih2 = W_ih[tid * 3 + 2] * scale;
    const float bg   = (b_ih[tid] + b_hh[tid]) * scale;
    const float bpj  = b_proj[lane];

    float cA = 0.0f, cB = 0.0f;        // unit `lane` state, per-wave copies
    int   pkA = 0,  pkB = 0;           // packed h pairs (valid on even lanes)
    float* outA = out + (size_t)b * (FUT_SEQ * H_SZ);
    float* outB = out + (size_t)(b + NBLK) * (FUT_SEQ * H_SZ);
    int next_cp = T_PAST_ + WSPF_ - 1;
    int cp_k = 0;

    __syncthreads();

    for (int t = 0; t < T_TOT; ++t) {
        // ---- element A dot (8 uniform b128 reads + 32 fdot2) ----
        const int4* hA4 = (const int4*)h2_lds[0][wv][t & 1];
        const int4* hB4 = (const int4*)h2_lds[1][wv][t & 1];
        float aA[4] = {bg, 0.f, 0.f, 0.f};
        float aB[4] = {bg, 0.f, 0.f, 0.f};
        #pragma unroll
        for (int q = 0; q < 8; ++q) {
            int4 pv = hA4[q];
            aA[0] = dot2_(w2[4*q+0], pv.x, aA[0]);
            aA[1] = dot2_(w2[4*q+1], pv.y, aA[1]);
            aA[2] = dot2_(w2[4*q+2], pv.z, aA[2]);
            aA[3] = dot2_(w2[4*q+3], pv.w, aA[3]);
        }
        #pragma unroll
        for (int q = 0; q < 8; ++q) {
            int4 pv = hB4[q];
            aB[0] = dot2_(w2[4*q+0], pv.x, aB[0]);
            aB[1] = dot2_(w2[4*q+1], pv.y, aB[1]);
            aB[2] = dot2_(w2[4*q+2], pv.z, aB[2]);
            aB[3] = dot2_(w2[4*q+3], pv.w, aB[3]);
        }
        // fold x contribution (uniform reads, hidden under the dots)
        aA[1] = fmaf(wih0, x_lds[0][t*3+0], aA[1]);
        aA[2] = fmaf(wih1, x_lds[0][t*3+1], aA[2]);
        aA[3] = fmaf(wih2, x_lds[0][t*3+2], aA[3]);
        aB[1] = fmaf(wih0, x_lds[1][t*3+0], aB[1]);
        aB[2] = fmaf(wih1, x_lds[1][t*3+1], aB[2]);
        aB[3] = fmaf(wih2, x_lds[1][t*3+2], aB[3]);

        float accA = (aA[0] + aA[1]) + (aA[2] + aA[3]);
        float accB = (aB[0] + aB[1]) + (aB[2] + aB[3]);
        float eA   = __expf(-accA);
        float eB   = __expf(-accB);
        float gvA  = fmaf(aa, rcp_(1.0f + eA), bb);    // sigmoid / tanh
        float gvB  = fmaf(aa, rcp_(1.0f + eB), bb);
        gates_lds[0][t & 1][tid] = gvA;
        gates_lds[1][t & 1][tid] = gvB;
        __syncthreads();               // gates(t) for A and B visible

        // ---- updates (all waves redundantly, unit `lane`) ----
        float giA = gates_lds[0][t & 1][0 * H_SZ + lane];
        float gfA = gates_lds[0][t & 1][1 * H_SZ + lane];
        float ggA = gates_lds[0][t & 1][2 * H_SZ + lane];
        float goA = gates_lds[0][t & 1][3 * H_SZ + lane];
        float giB = gates_lds[1][t & 1][0 * H_SZ + lane];
        float gfB = gates_lds[1][t & 1][1 * H_SZ + lane];
        float ggB = gates_lds[1][t & 1][2 * H_SZ + lane];
        float goB = gates_lds[1][t & 1][3 * H_SZ + lane];
        cA = fmaf(gfA, cA, giA * ggA);
        cB = fmaf(gfB, cB, giB * ggB);
        float hA = goA * tanh_(cA);
        float hB = goB * tanh_(cB);

        // pack pairs via DPP neighbor, write own wave's next-buf copies
        float hnA = dpp_xor1_(hA);
        float hnB = dpp_xor1_(hB);
        pkA = as_i(__builtin_amdgcn_cvt_pkrtz(hA, hnA));
        pkB = as_i(__builtin_amdgcn_cvt_pkrtz(hB, hnB));
        if ((lane & 1) == 0) {
            h2_lds[0][wv][(t + 1) & 1][lane >> 1] = pkA;
            h2_lds[1][wv][(t + 1) & 1][lane >> 1] = pkB;
        }
        // no 2nd barrier: per-wave h2 copies (in-wave ordering), gates
        // double-buffer tolerates <=1-step wave skew

        if (t == next_cp) {            // block-uniform condition
            if (wv == 0) {             // wave 0 projects A, wave 1 projects B
                float p = bpj;
                #pragma unroll
                for (int j = 0; j < 32; ++j) {
                    h2 hp = as_h2(rl_(pkA, 2 * j));
                    p = fmaf(wproj_lds[lane * PSTRIDE + 2*j    ], (float)hp.x, p);
                    p = fmaf(wproj_lds[lane * PSTRIDE + 2*j + 1], (float)hp.y, p);
                }
                outA[cp_k * H_SZ + lane] = p;
            } else if (wv == 1) {
                float p = bpj;
                #pragma unroll
                for (int j = 0; j < 32; ++j) {
                    h2 hp = as_h2(rl_(pkB, 2 * j));
                    p = fmaf(wproj_lds[lane * PSTRIDE + 2*j    ], (float)hp.x, p);
                    p = fmaf(wproj_lds[lane * PSTRIDE + 2*j + 1], (float)hp.y, p);
                }
                outB[cp_k * H_SZ + lane] = p;
            }
            next_cp += WSPF_;
            ++cp_k;
        }
    }
}

extern "C" void kernel_launch(void* const* d_in, const int* in_sizes, int n_in,
                              void* d_out, int out_size, void* d_ws, size_t ws_size,
                              hipStream_t stream) {
    const float* wave_input  = (const float*)d_in[0];
    const float* wave_future = (const float*)d_in[1];
    const float* W_ih        = (const float*)d_in[2];
    const float* W_hh        = (const float*)d_in[3];
    const float* b_ih        = (const float*)d_in[4];
    const float* b_hh        = (const float*)d_in[5];
    const float* W_proj      = (const float*)d_in[6];
    const float* b_proj      = (const float*)d_in[7];
    float* out               = (float*)d_out;

    lstm_fused_kernel<<<NBLK, NTHREADS, 0, stream>>>(
        wave_input, wave_future, W_ih, W_hh, b_ih, b_hh, W_proj, b_proj, out);
}

// Round 12
// 833.035 us; speedup vs baseline: 1.4386x; 1.4386x over previous
//
#include <hip/hip_runtime.h>
#include <math.h>

#define BATCH     512
#define T_PAST_   360
#define T_FUT_    1800
#define IN_SZ     3
#define H_SZ      64
#define FUT_SEQ   50
#define WSPF_     34
#define MAX_STEPS (FUT_SEQ * WSPF_)      // 1700
#define T_TOT     (T_PAST_ + MAX_STEPS)  // 2060
#define NTHREADS  256

typedef __fp16 h2 __attribute__((ext_vector_type(2)));

__device__ __forceinline__ h2  as_h2(int v) { return __builtin_bit_cast(h2, v); }
__device__ __forceinline__ int as_i(h2 v)   { return __builtin_bit_cast(int, v); }
__device__ __forceinline__ float rcp_(float x) { return __builtin_amdgcn_rcpf(x); }

__device__ __forceinline__ float tanh_(float x) {
    float a = fabsf(x);
    float e = __expf(-2.0f * a);         // in (0,1], no overflow
    float t = (1.0f - e) * rcp_(1.0f + e);
    return copysignf(t, x);
}

// packed-pair dot with f32 accumulate: D = a.x*b.x + a.y*b.y + c
__device__ __forceinline__ float dot2_(int a, int b, float c) {
#if __has_builtin(__builtin_amdgcn_fdot2)
    return __builtin_amdgcn_fdot2(as_h2(a), as_h2(b), c, false);
#else
    h2 av = as_h2(a), bv = as_h2(b);
    return fmaf((float)av.x, (float)bv.x, fmaf((float)av.y, (float)bv.y, c));
#endif
}

// DPP quad broadcast: every lane of a quad gets quad-lane `i`'s value
template <int PAT>
__device__ __forceinline__ float quadb_(float v) {
    return __builtin_bit_cast(float,
        __builtin_amdgcn_update_dpp(0, __builtin_bit_cast(int, v),
                                    PAT, 0xF, 0xF, true));
}

// lane L <- lane L^4 (ds_swizzle BitMode xor=4, in-wave, no barrier)
__device__ __forceinline__ float swz_xor4_(float v) {
    return __builtin_bit_cast(float,
        __builtin_amdgcn_ds_swizzle(__builtin_bit_cast(int, v), 0x101F));
}

// Thread = (unit, gate): wave w owns units 16w..16w+15, lane = 4*u_local + g.
// The 4 gate values of a unit live in ONE QUAD -> gathered by 4 DPP
// quad_perm broadcasts (pure VALU); c/h updated redundantly in all 4 quad
// lanes. r9's gates LDS round-trip (write + barrier + ~120cy read) is gone
// from the recurrent chain. Remaining per step: 8 uniform b128 h2 reads,
// 32 fdot2, exp, DPP gather, update, swizzle-pack, 8 lanes/wave h2 write,
// ONE barrier. LDS ~34 KB -> 2 blocks/CU (r11's 72KB killed co-residency).
__global__ __launch_bounds__(NTHREADS, 2)
void lstm_fused_kernel(const float* __restrict__ wave_input,   // [B, 360, 3]
                       const float* __restrict__ wave_future,  // [B, 1800, 3]
                       const float* __restrict__ W_ih,         // [256, 3]
                       const float* __restrict__ W_hh,         // [256, 64]
                       const float* __restrict__ b_ih,         // [256]
                       const float* __restrict__ b_hh,         // [256]
                       const float* __restrict__ W_proj,       // [64, 64]
                       const float* __restrict__ b_proj,       // [64]
                       float* __restrict__ out)                // [B, 50, 64]
{
    __shared__ __align__(16) float x_lds[T_TOT * IN_SZ];   // 24.7 KB
    __shared__ __align__(16) int   wp_lds[H_SZ * 33];      // packed W_proj, 8.4 KB
    __shared__ __align__(16) int   h2_lds[2][H_SZ / 2];    // packed h, 256 B

    const int b    = blockIdx.x;
    const int tid  = threadIdx.x;
    const int wv   = tid >> 6;
    const int lane = tid & 63;
    const int g    = lane & 3;          // gate: 0=i 1=f 2=g 3=o
    const int u    = wv * 16 + (lane >> 2);   // hidden unit
    const int row  = g * H_SZ + u;      // gate-matrix row

    // ---- stage x sequence (coalesced, one-time) ----
    {
        const float* wi = wave_input + (size_t)b * (T_PAST_ * IN_SZ);
        for (int i = tid; i < T_PAST_ * IN_SZ; i += NTHREADS) x_lds[i] = wi[i];
        const float* wf = wave_future + (size_t)b * (T_FUT_ * IN_SZ);
        for (int i = tid; i < MAX_STEPS * IN_SZ; i += NTHREADS)
            x_lds[T_PAST_ * IN_SZ + i] = wf[i];
    }
    // ---- W_proj rows packed fp16, stride 33 words: banks (j+m)%32, 2-way free ----
    for (int i = tid; i < H_SZ * 32; i += NTHREADS) {
        int j = i >> 5, m = i & 31;
        wp_lds[j * 33 + m] = as_i(__builtin_amdgcn_cvt_pkrtz(
            W_proj[j * H_SZ + 2 * m], W_proj[j * H_SZ + 2 * m + 1]));
    }
    if (tid < 32) h2_lds[0][tid] = 0;   // h(0) = 0

    // g-gate rows: fold tanh(x)=2*sigmoid(2x)-1 scale into weights/bias
    const float scale = (g == 2) ? 2.0f : 1.0f;
    const float aa    = (g == 2) ? 2.0f : 1.0f;
    const float bb    = (g == 2) ? -1.0f : 0.0f;

    // ---- W_hh row as 32 packed fp16 pairs (32 VGPRs, pinned) ----
    int w2[32];
    {
        const float* rowp = W_hh + (size_t)row * H_SZ;
        #pragma unroll
        for (int j = 0; j < 32; ++j)
            w2[j] = as_i(__builtin_amdgcn_cvt_pkrtz(rowp[2*j]   * scale,
                                                    rowp[2*j+1] * scale));
    }
    #pragma unroll
    for (int k = 0; k < 32; k += 8)
        asm volatile("" : "+v"(w2[k+0]), "+v"(w2[k+1]), "+v"(w2[k+2]), "+v"(w2[k+3]),
                          "+v"(w2[k+4]), "+v"(w2[k+5]), "+v"(w2[k+6]), "+v"(w2[k+7]));

    const float wih0 = W_ih[row * 3 + 0] * scale;
    const float wih1 = W_ih[row * 3 + 1] * scale;
    const float wih2 = W_ih[row * 3 + 2] * scale;
    const float bg   = (b_ih[row] + b_hh[row]) * scale;
    const float bpj  = b_proj[lane];

    float c = 0.0f;                     // unit u's cell state (quad-redundant)
    float* outb = out + (size_t)b * (FUT_SEQ * H_SZ);
    int next_cp = T_PAST_ + WSPF_ - 1;
    int cp_k = 0;

    __syncthreads();

    for (int t = 0; t < T_TOT; ++t) {
        // ---- dot: 8 uniform b128 broadcast reads + 32 fdot2 (4 chains) ----
        const int4* hp4 = (const int4*)h2_lds[t & 1];
        float a0 = bg, a1 = 0.f, a2 = 0.f, a3 = 0.f;
        #pragma unroll
        for (int q = 0; q < 8; ++q) {
            int4 pv = hp4[q];
            a0 = dot2_(w2[4*q+0], pv.x, a0);
            a1 = dot2_(w2[4*q+1], pv.y, a1);
            a2 = dot2_(w2[4*q+2], pv.z, a2);
            a3 = dot2_(w2[4*q+3], pv.w, a3);
        }
        a1 = fmaf(wih0, x_lds[t*3+0], a1);
        a2 = fmaf(wih1, x_lds[t*3+1], a2);
        a3 = fmaf(wih2, x_lds[t*3+2], a3);
        float acc = (a0 + a1) + (a2 + a3);

        float e    = __expf(-acc);
        float gval = fmaf(aa, rcp_(1.0f + e), bb);     // sigmoid / tanh

        // ---- quad gather (DPP broadcasts, no LDS) ----
        float gi = quadb_<0x00>(gval);
        float gf = quadb_<0x55>(gval);
        float gg = quadb_<0xAA>(gval);
        float go = quadb_<0xFF>(gval);
        c = fmaf(gf, c, gi * gg);
        float h = go * tanh_(c);        // all 4 quad lanes hold h_u

        // ---- pack (h_u, h_{u^1}) and publish: 8 lanes per wave write ----
        float hn = swz_xor4_(h);        // lane L <- h of unit u^1
        int pk = as_i(__builtin_amdgcn_cvt_pkrtz(h, hn));
        if ((lane & 7) == 0)            // even unit, gate 0
            h2_lds[(t + 1) & 1][wv * 8 + (lane >> 3)] = pk;
        __syncthreads();                // h(t) visible to all waves

        if (t == next_cp) {             // block-uniform
            // all waves compute redundantly (stay in lockstep); wave 0 writes
            const int4* ph4 = (const int4*)h2_lds[(t + 1) & 1];
            float p = bpj;
            #pragma unroll
            for (int q = 0; q < 8; ++q) {
                int4 pv = ph4[q];
                p = dot2_(wp_lds[lane * 33 + 4*q+0], pv.x, p);
                p = dot2_(wp_lds[lane * 33 + 4*q+1], pv.y, p);
                p = dot2_(wp_lds[lane * 33 + 4*q+2], pv.z, p);
                p = dot2_(wp_lds[lane * 33 + 4*q+3], pv.w, p);
            }
            if (wv == 0) outb[cp_k * H_SZ + lane] = p;
            next_cp += WSPF_;
            ++cp_k;
        }
    }
}

extern "C" void kernel_launch(void* const* d_in, const int* in_sizes, int n_in,
                              void* d_out, int out_size, void* d_ws, size_t ws_size,
                              hipStream_t stream) {
    const float* wave_input  = (const float*)d_in[0];
    const float* wave_future = (const float*)d_in[1];
    const float* W_ih        = (const float*)d_in[2];
    const float* W_hh        = (const float*)d_in[3];
    const float* b_ih        = (const float*)d_in[4];
    const float* b_hh        = (const float*)d_in[5];
    const float* W_proj      = (const float*)d_in[6];
    const float* b_proj      = (const float*)d_in[7];
    float* out               = (float*)d_out;

    lstm_fused_kernel<<<BATCH, NTHREADS, 0, stream>>>(
        wave_input, wave_future, W_ih, W_hh, b_ih, b_hh, W_proj, b_proj, out);
}